// Round 5
// baseline (451.581 us; speedup 1.0000x reference)
//
#include <hip/hip_runtime.h>

#define NEG_SLOPE 0.2f

typedef short bf16x8 __attribute__((ext_vector_type(8)));
typedef float f32x4 __attribute__((ext_vector_type(4)));

__device__ __forceinline__ float lrelu(float v) { return fmaxf(v, NEG_SLOPE * v); }

__device__ __forceinline__ unsigned short f2bf(float f) {
    union { float f; unsigned u; } v; v.f = f;
    unsigned r = v.u + 0x7fffu + ((v.u >> 16) & 1u);
    return (unsigned short)(r >> 16);
}
__device__ __forceinline__ float bf2f(unsigned short b) {
    union { unsigned u; float f; } v; v.u = ((unsigned)b) << 16;
    return v.f;
}

// ---------------------------------------------------------------------------
// Split + transpose the 4 weight matrices: Wt_hi/lo[m][n][k] = split(W[m][k][n])
// ---------------------------------------------------------------------------
__global__ __launch_bounds__(256) void wsplit_kernel(
    const float* __restrict__ W0, const float* __restrict__ W1,
    const float* __restrict__ W2, const float* __restrict__ W3,
    unsigned short* __restrict__ wt_hi, unsigned short* __restrict__ wt_lo)
{
    int idx = blockIdx.x * 256 + threadIdx.x;   // 4*128*128 total
    int m = idx >> 14;
    int k = (idx >> 7) & 127;
    int n = idx & 127;
    const float* W = (m == 0) ? W0 : (m == 1) ? W1 : (m == 2) ? W2 : W3;
    float f = W[k * 128 + n];
    unsigned short h = f2bf(f);
    unsigned short l = f2bf(f - bf2f(h));
    wt_hi[m * 16384 + n * 128 + k] = h;
    wt_lo[m * 16384 + n * 128 + k] = l;
}

__global__ __launch_bounds__(256) void xsplit_kernel(
    const float* __restrict__ x, unsigned short* __restrict__ xh,
    unsigned short* __restrict__ xlo, int total)
{
    int i = blockIdx.x * 256 + threadIdx.x;
    if (i * 2 < total) {
        float2 f = *(const float2*)(x + (size_t)i * 2);
        ushort2 h, l;
        h.x = f2bf(f.x); l.x = f2bf(f.x - bf2f(h.x));
        h.y = f2bf(f.y); l.y = f2bf(f.y - bf2f(h.y));
        *(ushort2*)(xh  + (size_t)i * 2) = h;
        *(ushort2*)(xlo + (size_t)i * 2) = l;
    }
}

// ---------------------------------------------------------------------------
// Split-bf16 MFMA GEMM, no LDS: B-fragments straight from global (W is
// 32 KB/pass -> L1-resident; all waves read it in the same order).
// C ~= Ah*Wh + Al*Wh + Ah*Wl, fp32 accumulate. Wave = 32 rows x 128 cols.
// ---------------------------------------------------------------------------
__global__ __launch_bounds__(256) void gemm_mfma_kernel(
    const unsigned short* __restrict__ Ahi, const unsigned short* __restrict__ Alo,
    const unsigned short* __restrict__ Wt0hi, const unsigned short* __restrict__ Wt0lo,
    const unsigned short* __restrict__ Wt1hi, const unsigned short* __restrict__ Wt1lo,
    float* __restrict__ C0, float* __restrict__ C1, int N)
{
    const unsigned short* Whi = blockIdx.y ? Wt1hi : Wt0hi;
    const unsigned short* Wlo = blockIdx.y ? Wt1lo : Wt0lo;
    float* C = blockIdx.y ? C1 : C0;

    const int tid  = threadIdx.x;
    const int wave = tid >> 6;
    const int lane = tid & 63;
    const int mrow = lane & 15;
    const int quad = lane >> 4;
    const int rbase = blockIdx.x * 128 + wave * 32;

    // A fragments: 2 row-tiles x 4 K-steps, hi+lo
    bf16x8 ah[2][4], al[2][4];
#pragma unroll
    for (int rt = 0; rt < 2; rt++) {
        int r = rbase + rt * 16 + mrow;
        if (r > N - 1) r = N - 1;
        const unsigned short* pa = Ahi + (size_t)r * 128 + quad * 8;
        const unsigned short* pl = Alo + (size_t)r * 128 + quad * 8;
#pragma unroll
        for (int s = 0; s < 4; s++) {
            ah[rt][s] = *(const bf16x8*)(pa + s * 32);
            al[rt][s] = *(const bf16x8*)(pl + s * 32);
        }
    }

    f32x4 acc[2][8];
#pragma unroll
    for (int rt = 0; rt < 2; rt++)
#pragma unroll
        for (int c = 0; c < 8; c++) acc[rt][c] = (f32x4){0.f, 0.f, 0.f, 0.f};

    // pass 1: W_hi  (Ah*Wh + Al*Wh)
    {
        const unsigned short* wb = Whi + (size_t)mrow * 128 + quad * 8;
#pragma unroll
        for (int s = 0; s < 4; s++) {
#pragma unroll
            for (int c = 0; c < 8; c++) {
                bf16x8 bh = *(const bf16x8*)(wb + c * (16 * 128) + s * 32);
                acc[0][c] = __builtin_amdgcn_mfma_f32_16x16x32_bf16(ah[0][s], bh, acc[0][c], 0, 0, 0);
                acc[1][c] = __builtin_amdgcn_mfma_f32_16x16x32_bf16(ah[1][s], bh, acc[1][c], 0, 0, 0);
                acc[0][c] = __builtin_amdgcn_mfma_f32_16x16x32_bf16(al[0][s], bh, acc[0][c], 0, 0, 0);
                acc[1][c] = __builtin_amdgcn_mfma_f32_16x16x32_bf16(al[1][s], bh, acc[1][c], 0, 0, 0);
            }
        }
    }
    // pass 2: W_lo  (Ah*Wl)
    {
        const unsigned short* wb = Wlo + (size_t)mrow * 128 + quad * 8;
#pragma unroll
        for (int s = 0; s < 4; s++) {
#pragma unroll
            for (int c = 0; c < 8; c++) {
                bf16x8 bl = *(const bf16x8*)(wb + c * (16 * 128) + s * 32);
                acc[0][c] = __builtin_amdgcn_mfma_f32_16x16x32_bf16(ah[0][s], bl, acc[0][c], 0, 0, 0);
                acc[1][c] = __builtin_amdgcn_mfma_f32_16x16x32_bf16(ah[1][s], bl, acc[1][c], 0, 0, 0);
            }
        }
    }

    // D mapping: col = lane&15, row = quad*4 + reg
#pragma unroll
    for (int rt = 0; rt < 2; rt++) {
#pragma unroll
        for (int i = 0; i < 4; i++) {
            int r = rbase + rt * 16 + quad * 4 + i;
            if (r < N) {
                float* cr = C + (size_t)r * 128 + mrow;
#pragma unroll
                for (int c = 0; c < 8; c++) cr[c * 16] = acc[rt][c][i];
            }
        }
    }
}

// ---------------------------------------------------------------------------
// Counting sort of edges by dst — hist, hierarchical scan, scatter
// ---------------------------------------------------------------------------
__global__ __launch_bounds__(256) void hist_kernel(
    const int* __restrict__ ei, int* __restrict__ cnt, int E)
{
    int e = blockIdx.x * 256 + threadIdx.x;
    if (e < E) atomicAdd(cnt + ei[E + e], 1);
}

__global__ __launch_bounds__(256) void blockscan_kernel(
    const int* __restrict__ cnt, int* __restrict__ excl,
    int* __restrict__ bsum, int N)
{
    __shared__ int s[256];
    int tid = threadIdx.x;
    int i = blockIdx.x * 256 + tid;
    int v = (i < N) ? cnt[i] : 0;
    s[tid] = v;
    __syncthreads();
    for (int off = 1; off < 256; off <<= 1) {
        int t = (tid >= off) ? s[tid - off] : 0;
        __syncthreads();
        s[tid] += t;
        __syncthreads();
    }
    if (i < N) excl[i] = s[tid] - v;
    if (tid == 255) bsum[blockIdx.x] = s[255];
}

__global__ __launch_bounds__(256) void topscan_kernel(
    const int* __restrict__ bsum, int* __restrict__ boff, int G)
{
    __shared__ int s[256];
    int tid = threadIdx.x;
    int v = (tid < G) ? bsum[tid] : 0;
    s[tid] = v;
    __syncthreads();
    for (int off = 1; off < 256; off <<= 1) {
        int t = (tid >= off) ? s[tid - off] : 0;
        __syncthreads();
        s[tid] += t;
        __syncthreads();
    }
    if (tid < G) boff[tid] = s[tid] - v;
}

__global__ __launch_bounds__(256) void addoff_kernel(
    int* __restrict__ start, int* __restrict__ cursor,
    const int* __restrict__ boff, int N, int E)
{
    int i = blockIdx.x * 256 + threadIdx.x;
    if (i < N) {
        int t = start[i] + boff[blockIdx.x];
        start[i] = t;
        cursor[i] = t;
    }
    if (i == 0) start[N] = E;
}

__global__ __launch_bounds__(256) void scatter_kernel(
    const int* __restrict__ ei, int* __restrict__ cursor,
    int* __restrict__ sorted_src, int E)
{
    int e = blockIdx.x * 256 + threadIdx.x;
    if (e < E) {
        int pos = atomicAdd(cursor + ei[E + e], 1);
        sorted_src[pos] = ei[e];
    }
}

// ---------------------------------------------------------------------------
// Fused score+softmax+aggregate v2: one wave per dst node; each HALF-WAVE
// (32 lanes x float4) owns its own edge -> 2 edges per wave-iteration,
// dwordx4 gathers, 4-deep (H=2) / 5-deep (H=1) swizzle reduce shared by
// both edges, one expf per 2 edges. Unrolled 4 per half (8 edges in flight).
// Virtual edge 0 = self-loop (processed by half 0 only).
// ---------------------------------------------------------------------------
template <int H, bool BFOUT>
__global__ __launch_bounds__(256) void gat_fused_kernel(
    const float* __restrict__ xl, const float* __restrict__ xr,
    const float* __restrict__ att, const float* __restrict__ bias,
    const int* __restrict__ start, const int* __restrict__ sorted_src,
    float* __restrict__ outf, unsigned short* __restrict__ oh,
    unsigned short* __restrict__ ol, int N)
{
    int node = blockIdx.x * 4 + (threadIdx.x >> 6);
    if (node >= N) return;
    const int lane = threadIdx.x & 63;
    const int half = lane >> 5;
    const int hl   = lane & 31;
    const int RED  = (H == 2) ? 8 : 16;   // xor masks 1..RED within half-wave

    const float4 b  = *(const float4*)(xr + (size_t)node * 128 + hl * 4);
    const float4 av = *(const float4*)(att + hl * 4);

    float4 acc = make_float4(0.f, 0.f, 0.f, 0.f);
    float den = 0.f;

    const int s0 = start[node];
    const int s1 = start[node + 1];
    const int M  = s1 - s0 + 1;        // incl. self-loop at iv==0
    const int Ksafe = (M - 1) >> 1;    // k < Ksafe: both halves valid
    const int K     = (M + 1) >> 1;

    int k = 0;
    for (; k + 4 <= Ksafe; k += 4) {
        int src[4];
#pragma unroll
        for (int j = 0; j < 4; j++) {
            int iv = 2 * (k + j) + half;
            src[j] = (iv == 0) ? node : sorted_src[s0 + iv - 1];
        }
        float4 a[4];
#pragma unroll
        for (int j = 0; j < 4; j++)
            a[j] = *(const float4*)(xl + (size_t)src[j] * 128 + hl * 4);
        float p[4];
#pragma unroll
        for (int j = 0; j < 4; j++) {
            float t0 = lrelu(a[j].x + b.x);
            float t1 = lrelu(a[j].y + b.y);
            float t2 = lrelu(a[j].z + b.z);
            float t3 = lrelu(a[j].w + b.w);
            p[j] = t0 * av.x + t1 * av.y + t2 * av.z + t3 * av.w;
        }
#pragma unroll
        for (int m = 1; m <= RED; m <<= 1) {
#pragma unroll
            for (int j = 0; j < 4; j++) p[j] += __shfl_xor(p[j], m, 64);
        }
#pragma unroll
        for (int j = 0; j < 4; j++) {
            float e = __expf(p[j]);
            den += e;
            acc.x += e * a[j].x; acc.y += e * a[j].y;
            acc.z += e * a[j].z; acc.w += e * a[j].w;
        }
    }
    for (; k < Ksafe; k++) {
        int iv = 2 * k + half;
        int src = (iv == 0) ? node : sorted_src[s0 + iv - 1];
        float4 a = *(const float4*)(xl + (size_t)src * 128 + hl * 4);
        float p = lrelu(a.x + b.x) * av.x + lrelu(a.y + b.y) * av.y
                + lrelu(a.z + b.z) * av.z + lrelu(a.w + b.w) * av.w;
#pragma unroll
        for (int m = 1; m <= RED; m <<= 1) p += __shfl_xor(p, m, 64);
        float e = __expf(p);
        den += e;
        acc.x += e * a.x; acc.y += e * a.y; acc.z += e * a.z; acc.w += e * a.w;
    }
    for (; k < K; k++) {             // masked tail (exactly one iteration)
        int iv = 2 * k + half;
        bool valid = iv < M;
        int pos = s0 + (iv > 0 ? iv - 1 : 0);   // sorted_src padded by 16 ints
        int ld = sorted_src[pos];
        int src = (iv == 0) ? node : (valid ? ld : node);
        float4 a = *(const float4*)(xl + (size_t)src * 128 + hl * 4);
        float p = lrelu(a.x + b.x) * av.x + lrelu(a.y + b.y) * av.y
                + lrelu(a.z + b.z) * av.z + lrelu(a.w + b.w) * av.w;
#pragma unroll
        for (int m = 1; m <= RED; m <<= 1) p += __shfl_xor(p, m, 64);
        float e = valid ? __expf(p) : 0.f;
        den += e;
        acc.x += e * a.x; acc.y += e * a.y; acc.z += e * a.z; acc.w += e * a.w;
    }

    // merge the two halves' edge streams
    den   += __shfl_xor(den,   32, 64);
    acc.x += __shfl_xor(acc.x, 32, 64);
    acc.y += __shfl_xor(acc.y, 32, 64);
    acc.z += __shfl_xor(acc.z, 32, 64);
    acc.w += __shfl_xor(acc.w, 32, 64);

    float inv = 1.0f / den;
    float4 bi = *(const float4*)(bias + hl * 4);
    float o0 = acc.x * inv + bi.x;
    float o1 = acc.y * inv + bi.y;
    float o2 = acc.z * inv + bi.z;
    float o3 = acc.w * inv + bi.w;

    if (lane < 32) {
        if (BFOUT) {
            unsigned short h0 = f2bf(o0), h1 = f2bf(o1), h2 = f2bf(o2), h3 = f2bf(o3);
            ushort4 hv; hv.x = h0; hv.y = h1; hv.z = h2; hv.w = h3;
            ushort4 lv;
            lv.x = f2bf(o0 - bf2f(h0)); lv.y = f2bf(o1 - bf2f(h1));
            lv.z = f2bf(o2 - bf2f(h2)); lv.w = f2bf(o3 - bf2f(h3));
            *(ushort4*)(oh + (size_t)node * 128 + hl * 4) = hv;
            *(ushort4*)(ol + (size_t)node * 128 + hl * 4) = lv;
        } else {
            *(float4*)(outf + (size_t)node * 128 + hl * 4) = make_float4(o0, o1, o2, o3);
        }
    }
}

// ---------------------------------------------------------------------------
extern "C" void kernel_launch(void* const* d_in, const int* in_sizes, int n_in,
                              void* d_out, int out_size, void* d_ws, size_t ws_size,
                              hipStream_t stream)
{
    const float* x    = (const float*)d_in[0];
    const int*   ei   = (const int*)d_in[1];
    const float* Wl1  = (const float*)d_in[3];
    const float* Wr1  = (const float*)d_in[4];
    const float* att1 = (const float*)d_in[5];
    const float* b1   = (const float*)d_in[6];
    const float* Wl2  = (const float*)d_in[7];
    const float* Wr2  = (const float*)d_in[8];
    const float* att2 = (const float*)d_in[9];
    const float* b2   = (const float*)d_in[10];
    float* out = (float*)d_out;

    const int N = in_sizes[0] / 128;
    const int E = in_sizes[1] / 2;

    const size_t nf = (size_t)N * 128;
    float* xl = (float*)d_ws;                         // N*128 f32
    float* xr = xl + nf;                              // N*128 f32
    unsigned short* xh  = (unsigned short*)(xr + nf); // N*128 bf16 (A_hi; reused as h_hi)
    unsigned short* xlo = xh + nf;                    // N*128 bf16 (A_lo; reused as h_lo)
    unsigned short* wt_hi = xlo + nf;                 // 4*128*128 bf16
    unsigned short* wt_lo = wt_hi + 4 * 16384;        // 4*128*128 bf16
    int* cnt        = (int*)(wt_lo + 4 * 16384);      // N
    int* start      = cnt + N;                        // N+1
    int* cursor     = start + N + 1;                  // N
    int* bsum       = cursor + N;                     // 256
    int* boff       = bsum + 256;                     // 256
    int* sorted_src = boff + 256;                     // E + 16 (padded for masked tail)

    const int G          = (N + 255) / 256;
    const int edge_grid  = (E + 255) / 256;
    const int node_grid  = (N + 3) / 4;
    const int gemm_gx    = (N + 127) / 128;
    const int split_grid = (int)((nf / 2 + 255) / 256);

    // ---- precompute: weight transpose+split, x split ----
    wsplit_kernel<<<256, 256, 0, stream>>>(Wl1, Wr1, Wl2, Wr2, wt_hi, wt_lo);
    xsplit_kernel<<<split_grid, 256, 0, stream>>>(x, xh, xlo, (int)nf);

    // ---- edge sort by dst (shared by both layers) ----
    hipMemsetAsync(cnt, 0, (size_t)N * sizeof(int), stream);
    hist_kernel<<<edge_grid, 256, 0, stream>>>(ei, cnt, E);
    blockscan_kernel<<<G, 256, 0, stream>>>(cnt, start, bsum, N);
    topscan_kernel<<<1, 256, 0, stream>>>(bsum, boff, G);
    addoff_kernel<<<G, 256, 0, stream>>>(start, cursor, boff, N, E);
    scatter_kernel<<<edge_grid, 256, 0, stream>>>(ei, cursor, sorted_src, E);

    // ---- Layer 1: heads=2, ch=64 ----
    gemm_mfma_kernel<<<dim3(gemm_gx, 2), 256, 0, stream>>>(
        xh, xlo, wt_hi + 0 * 16384, wt_lo + 0 * 16384,
        wt_hi + 1 * 16384, wt_lo + 1 * 16384, xl, xr, N);
    gat_fused_kernel<2, true><<<node_grid, 256, 0, stream>>>(
        xl, xr, att1, b1, start, sorted_src, nullptr, xh, xlo, N);

    // ---- Layer 2: heads=1, ch=128 ----  (A = h, already split in xh/xlo)
    gemm_mfma_kernel<<<dim3(gemm_gx, 2), 256, 0, stream>>>(
        xh, xlo, wt_hi + 2 * 16384, wt_lo + 2 * 16384,
        wt_hi + 3 * 16384, wt_lo + 3 * 16384, xl, xr, N);
    gat_fused_kernel<1, false><<<node_grid, 256, 0, stream>>>(
        xl, xr, att2, b2, start, sorted_src, out, nullptr, nullptr, N);
}

// Round 6
// 316.678 us; speedup vs baseline: 1.4260x; 1.4260x over previous
//
#include <hip/hip_runtime.h>

#define NEG_SLOPE 0.2f
#define NPB 256          // nodes per dst-bucket (bucket = dst >> 8)
#define CHUNK 4096       // edges per partition block

typedef _Float16 f16x8 __attribute__((ext_vector_type(8)));
typedef _Float16 f16x4 __attribute__((ext_vector_type(4)));
typedef _Float16 f16x2 __attribute__((ext_vector_type(2)));
typedef float    f32x4 __attribute__((ext_vector_type(4)));

__device__ __forceinline__ float lrelu(float v) { return fmaxf(v, NEG_SLOPE * v); }

__device__ __forceinline__ float4 ldf16x4(const _Float16* p) {
    f16x4 v = *(const f16x4*)p;
    return make_float4((float)v[0], (float)v[1], (float)v[2], (float)v[3]);
}

// ---------------------------------------------------------------------------
// Weights: transpose + round to fp16.  wt[m][n][k] = (f16) W_m[k][n]
// ---------------------------------------------------------------------------
__global__ __launch_bounds__(256) void wsplit_kernel(
    const float* __restrict__ W0, const float* __restrict__ W1,
    const float* __restrict__ W2, const float* __restrict__ W3,
    _Float16* __restrict__ wt)
{
    int idx = blockIdx.x * 256 + threadIdx.x;   // 4*128*128
    int m = idx >> 14;
    int k = (idx >> 7) & 127;
    int n = idx & 127;
    const float* W = (m == 0) ? W0 : (m == 1) ? W1 : (m == 2) ? W2 : W3;
    wt[m * 16384 + n * 128 + k] = (_Float16)W[k * 128 + n];
}

// x fp32 -> fp16 hi + lo (hi+lo reproduces x to ~2^-22)
__global__ __launch_bounds__(256) void xsplit_kernel(
    const float* __restrict__ x, _Float16* __restrict__ xh,
    _Float16* __restrict__ xlo, int total)
{
    int i = blockIdx.x * 256 + threadIdx.x;
    if (i * 2 < total) {
        float2 f = *(const float2*)(x + (size_t)i * 2);
        _Float16 h0 = (_Float16)f.x, h1 = (_Float16)f.y;
        _Float16 l0 = (_Float16)(f.x - (float)h0), l1 = (_Float16)(f.y - (float)h1);
        *(f16x2*)(xh  + (size_t)i * 2) = (f16x2){h0, h1};
        *(f16x2*)(xlo + (size_t)i * 2) = (f16x2){l0, l1};
    }
}

// ---------------------------------------------------------------------------
// fp16 MFMA GEMM, LDS-staged W (34 KB -> 4 blocks/CU), 2 MFMA per fragment:
// C = Ah@W + Al@W  (W rounded to fp16: err ~5e-4; A split exact).
// y==0 -> write C as fp16 (gather array xl); y==1 -> write fp32 (xr).
// ---------------------------------------------------------------------------
__global__ __launch_bounds__(256) void gemm_f16_kernel(
    const _Float16* __restrict__ Ahi, const _Float16* __restrict__ Alo,
    const _Float16* __restrict__ Wt0, const _Float16* __restrict__ Wt1,
    _Float16* __restrict__ Cl, float* __restrict__ Cr, int N)
{
    const _Float16* Wt = blockIdx.y ? Wt1 : Wt0;

    // row stride 136 halves = 272 B: 16B-aligned, 2-way bank alias (free)
    __shared__ _Float16 ldsW[128 * 136];

    const int tid = threadIdx.x;
    {   // stage 32 KB of W: thread -> row n = tid>>1, half = tid&1 (64 halves)
        int n = tid >> 1, hf = tid & 1;
        const float4* g = (const float4*)(Wt + n * 128 + hf * 64);
        float4* d = (float4*)&ldsW[n * 136 + hf * 64];
#pragma unroll
        for (int j = 0; j < 8; j++) d[j] = g[j];
    }

    const int wave = tid >> 6;
    const int lane = tid & 63;
    const int mrow = lane & 15;
    const int quad = lane >> 4;
    const int rbase = blockIdx.x * 128 + wave * 32;

    f16x8 ah[2][4], al[2][4];
#pragma unroll
    for (int rt = 0; rt < 2; rt++) {
        int r = rbase + rt * 16 + mrow;
        if (r > N - 1) r = N - 1;
        const _Float16* pa = Ahi + (size_t)r * 128 + quad * 8;
        const _Float16* pl = Alo + (size_t)r * 128 + quad * 8;
#pragma unroll
        for (int s = 0; s < 4; s++) {
            ah[rt][s] = *(const f16x8*)(pa + s * 32);
            al[rt][s] = *(const f16x8*)(pl + s * 32);
        }
    }

    f32x4 acc[2][8];
#pragma unroll
    for (int rt = 0; rt < 2; rt++)
#pragma unroll
        for (int c = 0; c < 8; c++) acc[rt][c] = (f32x4){0.f, 0.f, 0.f, 0.f};

    __syncthreads();

#pragma unroll
    for (int s = 0; s < 4; s++) {
#pragma unroll
        for (int c = 0; c < 8; c++) {
            f16x8 bw = *(const f16x8*)&ldsW[(c * 16 + mrow) * 136 + s * 32 + quad * 8];
            acc[0][c] = __builtin_amdgcn_mfma_f32_16x16x32_f16(ah[0][s], bw, acc[0][c], 0, 0, 0);
            acc[0][c] = __builtin_amdgcn_mfma_f32_16x16x32_f16(al[0][s], bw, acc[0][c], 0, 0, 0);
            acc[1][c] = __builtin_amdgcn_mfma_f32_16x16x32_f16(ah[1][s], bw, acc[1][c], 0, 0, 0);
            acc[1][c] = __builtin_amdgcn_mfma_f32_16x16x32_f16(al[1][s], bw, acc[1][c], 0, 0, 0);
        }
    }

    // D mapping: col = lane&15, row = quad*4 + reg
    if (blockIdx.y == 0) {
#pragma unroll
        for (int rt = 0; rt < 2; rt++)
#pragma unroll
            for (int i = 0; i < 4; i++) {
                int r = rbase + rt * 16 + quad * 4 + i;
                if (r < N) {
                    _Float16* cr = Cl + (size_t)r * 128 + mrow;
#pragma unroll
                    for (int c = 0; c < 8; c++) cr[c * 16] = (_Float16)acc[rt][c][i];
                }
            }
    } else {
#pragma unroll
        for (int rt = 0; rt < 2; rt++)
#pragma unroll
            for (int i = 0; i < 4; i++) {
                int r = rbase + rt * 16 + quad * 4 + i;
                if (r < N) {
                    float* cr = Cr + (size_t)r * 128 + mrow;
#pragma unroll
                    for (int c = 0; c < 8; c++) cr[c * 16] = acc[rt][c][i];
                }
            }
    }
}

// ---------------------------------------------------------------------------
// Bucketed CSR build (bucket = dst>>8). All heavy writes are XCD-local or
// coalesced runs -> no 64B-line write amplification.
// ---------------------------------------------------------------------------
__global__ __launch_bounds__(256) void histB_kernel(
    const int* __restrict__ ei, int* __restrict__ bcnt, int E)
{
    __shared__ int bh[256];
    int t = threadIdx.x;
    bh[t] = 0;
    __syncthreads();
    int base = blockIdx.x * CHUNK;
#pragma unroll
    for (int j = 0; j < CHUNK / 256; j++) {
        int e = base + t + j * 256;
        if (e < E) atomicAdd(&bh[ei[E + e] >> 8], 1);
    }
    __syncthreads();
    if (bh[t]) atomicAdd(&bcnt[t], bh[t]);
}

__global__ __launch_bounds__(256) void scanB_kernel(
    const int* __restrict__ bcnt, int* __restrict__ bstart,
    int* __restrict__ gcursor, int NB, int E)
{
    __shared__ int s[256];
    int t = threadIdx.x;
    int v = (t < NB) ? bcnt[t] : 0;
    s[t] = v;
    __syncthreads();
    for (int off = 1; off < 256; off <<= 1) {
        int u = (t >= off) ? s[t - off] : 0;
        __syncthreads();
        s[t] += u;
        __syncthreads();
    }
    if (t < NB) { bstart[t] = s[t] - v; gcursor[t] = s[t] - v; }
    if (t == 0) bstart[NB] = E;
}

// partition edges into bucket-contiguous staging (int2 = {src, dst})
__global__ __launch_bounds__(256) void passA_kernel(
    const int* __restrict__ ei, int* __restrict__ gcursor,
    int2* __restrict__ staging, int E)
{
    __shared__ int bh[256];
    __shared__ int bbase[256];
    int t = threadIdx.x;
    bh[t] = 0;
    __syncthreads();
    int base = blockIdx.x * CHUNK;
    int srcv[16], dstv[16], rb[16];
#pragma unroll
    for (int j = 0; j < 16; j++) {
        int e = base + t + j * 256;
        if (e < E) {
            int d = ei[E + e];
            srcv[j] = ei[e];
            dstv[j] = d;
            int bk = d >> 8;
            int r = atomicAdd(&bh[bk], 1);
            rb[j] = (r << 8) | bk;
        } else rb[j] = -1;
    }
    __syncthreads();
    if (bh[t]) bbase[t] = atomicAdd(&gcursor[t], bh[t]);
    __syncthreads();
#pragma unroll
    for (int j = 0; j < 16; j++) {
        if (rb[j] >= 0) {
            int bk = rb[j] & 255, r = rb[j] >> 8;
            staging[bbase[bk] + r] = make_int2(srcv[j], dstv[j]);
        }
    }
}

// per-bucket counting sort: emits sorted_src AND per-node start[] (CSR)
__global__ __launch_bounds__(256) void passB_kernel(
    const int2* __restrict__ staging, const int* __restrict__ bstart,
    int* __restrict__ start, int* __restrict__ sorted_src, int N, int E)
{
    __shared__ int lhist[256], lscan[256], lcur[256];
    int b = blockIdx.x, t = threadIdx.x;
    int r0 = bstart[b], r1 = bstart[b + 1];
    lhist[t] = 0;
    __syncthreads();
    for (int i = r0 + t; i < r1; i += 256) atomicAdd(&lhist[staging[i].y & 255], 1);
    __syncthreads();
    int v = lhist[t];
    lscan[t] = v;
    __syncthreads();
    for (int off = 1; off < 256; off <<= 1) {
        int u = (t >= off) ? lscan[t - off] : 0;
        __syncthreads();
        lscan[t] += u;
        __syncthreads();
    }
    int excl = lscan[t] - v;
    int node = b * NPB + t;
    if (node < N) start[node] = r0 + excl;
    lcur[t] = excl;
    if (b == 0 && t == 0) start[N] = E;
    __syncthreads();
    for (int i = r0 + t; i < r1; i += 256) {
        int2 p = staging[i];
        int rank = atomicAdd(&lcur[p.y & 255], 1);
        sorted_src[r0 + rank] = p.x;   // all writes to this region from ONE CU
    }
}

// ---------------------------------------------------------------------------
// Fused score+softmax+aggregate: one wave per dst node; each half-wave owns
// an edge (fp16 gather rows, 8B/lane). Self-loop = virtual edge 0.
// ---------------------------------------------------------------------------
template <int H, bool BFOUT>
__global__ __launch_bounds__(256) void gat_fused_kernel(
    const _Float16* __restrict__ xl, const float* __restrict__ xr,
    const float* __restrict__ att, const float* __restrict__ bias,
    const int* __restrict__ start, const int* __restrict__ sorted_src,
    float* __restrict__ outf, _Float16* __restrict__ oh,
    _Float16* __restrict__ ol, int N)
{
    int node = blockIdx.x * 4 + (threadIdx.x >> 6);
    if (node >= N) return;
    const int lane = threadIdx.x & 63;
    const int half = lane >> 5;
    const int hl   = lane & 31;
    const int RED  = (H == 2) ? 8 : 16;

    const float4 b  = *(const float4*)(xr + (size_t)node * 128 + hl * 4);
    const float4 av = *(const float4*)(att + hl * 4);

    float4 acc = make_float4(0.f, 0.f, 0.f, 0.f);
    float den = 0.f;

    const int s0 = start[node];
    const int s1 = start[node + 1];
    const int M  = s1 - s0 + 1;        // incl. self-loop at iv==0
    const int Ksafe = (M - 1) >> 1;
    const int K     = (M + 1) >> 1;

    int k = 0;
    for (; k + 4 <= Ksafe; k += 4) {
        int src[4];
#pragma unroll
        for (int j = 0; j < 4; j++) {
            int iv = 2 * (k + j) + half;
            src[j] = (iv == 0) ? node : sorted_src[s0 + iv - 1];
        }
        float4 a[4];
#pragma unroll
        for (int j = 0; j < 4; j++)
            a[j] = ldf16x4(xl + (size_t)src[j] * 128 + hl * 4);
        float p[4];
#pragma unroll
        for (int j = 0; j < 4; j++) {
            p[j] = lrelu(a[j].x + b.x) * av.x + lrelu(a[j].y + b.y) * av.y
                 + lrelu(a[j].z + b.z) * av.z + lrelu(a[j].w + b.w) * av.w;
        }
#pragma unroll
        for (int m = 1; m <= RED; m <<= 1) {
#pragma unroll
            for (int j = 0; j < 4; j++) p[j] += __shfl_xor(p[j], m, 64);
        }
#pragma unroll
        for (int j = 0; j < 4; j++) {
            float e = __expf(p[j]);
            den += e;
            acc.x += e * a[j].x; acc.y += e * a[j].y;
            acc.z += e * a[j].z; acc.w += e * a[j].w;
        }
    }
    for (; k < Ksafe; k++) {
        int iv = 2 * k + half;
        int src = (iv == 0) ? node : sorted_src[s0 + iv - 1];
        float4 a = ldf16x4(xl + (size_t)src * 128 + hl * 4);
        float p = lrelu(a.x + b.x) * av.x + lrelu(a.y + b.y) * av.y
                + lrelu(a.z + b.z) * av.z + lrelu(a.w + b.w) * av.w;
#pragma unroll
        for (int m = 1; m <= RED; m <<= 1) p += __shfl_xor(p, m, 64);
        float e = __expf(p);
        den += e;
        acc.x += e * a.x; acc.y += e * a.y; acc.z += e * a.z; acc.w += e * a.w;
    }
    for (; k < K; k++) {               // masked tail (one iteration)
        int iv = 2 * k + half;
        bool valid = iv < M;
        int pos = s0 + (iv > 0 ? iv - 1 : 0);   // sorted_src padded
        int ld = sorted_src[pos];
        int src = (iv == 0) ? node : (valid ? ld : node);
        float4 a = ldf16x4(xl + (size_t)src * 128 + hl * 4);
        float p = lrelu(a.x + b.x) * av.x + lrelu(a.y + b.y) * av.y
                + lrelu(a.z + b.z) * av.z + lrelu(a.w + b.w) * av.w;
#pragma unroll
        for (int m = 1; m <= RED; m <<= 1) p += __shfl_xor(p, m, 64);
        float e = valid ? __expf(p) : 0.f;
        den += e;
        acc.x += e * a.x; acc.y += e * a.y; acc.z += e * a.z; acc.w += e * a.w;
    }

    den   += __shfl_xor(den,   32, 64);
    acc.x += __shfl_xor(acc.x, 32, 64);
    acc.y += __shfl_xor(acc.y, 32, 64);
    acc.z += __shfl_xor(acc.z, 32, 64);
    acc.w += __shfl_xor(acc.w, 32, 64);

    float inv = 1.0f / den;
    float4 bi = *(const float4*)(bias + hl * 4);
    float o0 = acc.x * inv + bi.x;
    float o1 = acc.y * inv + bi.y;
    float o2 = acc.z * inv + bi.z;
    float o3 = acc.w * inv + bi.w;

    if (lane < 32) {
        if (BFOUT) {   // next layer's A: fp16 hi+lo split
            _Float16 h0 = (_Float16)o0, h1 = (_Float16)o1, h2 = (_Float16)o2, h3 = (_Float16)o3;
            f16x4 hv = {h0, h1, h2, h3};
            f16x4 lv = {(_Float16)(o0 - (float)h0), (_Float16)(o1 - (float)h1),
                        (_Float16)(o2 - (float)h2), (_Float16)(o3 - (float)h3)};
            *(f16x4*)(oh + (size_t)node * 128 + hl * 4) = hv;
            *(f16x4*)(ol + (size_t)node * 128 + hl * 4) = lv;
        } else {
            *(float4*)(outf + (size_t)node * 128 + hl * 4) = make_float4(o0, o1, o2, o3);
        }
    }
}

// ---------------------------------------------------------------------------
extern "C" void kernel_launch(void* const* d_in, const int* in_sizes, int n_in,
                              void* d_out, int out_size, void* d_ws, size_t ws_size,
                              hipStream_t stream)
{
    const float* x    = (const float*)d_in[0];
    const int*   ei   = (const int*)d_in[1];
    const float* Wl1  = (const float*)d_in[3];
    const float* Wr1  = (const float*)d_in[4];
    const float* att1 = (const float*)d_in[5];
    const float* b1   = (const float*)d_in[6];
    const float* Wl2  = (const float*)d_in[7];
    const float* Wr2  = (const float*)d_in[8];
    const float* att2 = (const float*)d_in[9];
    const float* b2   = (const float*)d_in[10];
    float* out = (float*)d_out;

    const int N  = in_sizes[0] / 128;
    const int E  = in_sizes[1] / 2;
    const int NB = (N + NPB - 1) / NPB;

    const size_t nf = (size_t)N * 128;
    float* xr      = (float*)d_ws;                    // nf f32
    _Float16* xlf  = (_Float16*)(xr + nf);            // nf fp16 (gather array)
    _Float16* ah   = xlf + nf;                        // nf fp16 (A hi: x, then h)
    _Float16* al   = ah + nf;                         // nf fp16 (A lo)
    _Float16* wt   = al + nf;                         // 4*16384 fp16
    int* bcnt      = (int*)(wt + 4 * 16384);          // 256
    int* bstart    = bcnt + 256;                      // NB+1 (<=257)
    int* gcursor   = bstart + 257;                    // 256
    int* start     = gcursor + 256;                   // N+1
    size_t stgoff  = ((size_t)(start + N + 1) + 7) & ~(size_t)7;
    int2* staging  = (int2*)stgoff;                   // E int2
    int* sorted_src = (int*)(staging + E);            // E + 64 (padded)

    const int grid_chunk = (E + CHUNK - 1) / CHUNK;
    const int node_grid  = (N + 3) / 4;
    const int gemm_gx    = (N + 127) / 128;
    const int split_grid = (int)((nf / 2 + 255) / 256);

    // ---- precompute: W transpose->fp16, x split ----
    wsplit_kernel<<<256, 256, 0, stream>>>(Wl1, Wr1, Wl2, Wr2, wt);
    xsplit_kernel<<<split_grid, 256, 0, stream>>>(x, ah, al, (int)nf);

    // ---- bucketed CSR build (shared by both layers) ----
    hipMemsetAsync(bcnt, 0, 256 * sizeof(int), stream);
    histB_kernel<<<grid_chunk, 256, 0, stream>>>(ei, bcnt, E);
    scanB_kernel<<<1, 256, 0, stream>>>(bcnt, bstart, gcursor, NB, E);
    passA_kernel<<<grid_chunk, 256, 0, stream>>>(ei, gcursor, staging, E);
    passB_kernel<<<NB, 256, 0, stream>>>(staging, bstart, start, sorted_src, N, E);

    // ---- Layer 1: heads=2, ch=64 ----
    gemm_f16_kernel<<<dim3(gemm_gx, 2), 256, 0, stream>>>(
        ah, al, wt + 0 * 16384, wt + 1 * 16384, xlf, xr, N);
    gat_fused_kernel<2, true><<<node_grid, 256, 0, stream>>>(
        xlf, xr, att1, b1, start, sorted_src, nullptr, ah, al, N);

    // ---- Layer 2: heads=1, ch=128 ----
    gemm_f16_kernel<<<dim3(gemm_gx, 2), 256, 0, stream>>>(
        ah, al, wt + 2 * 16384, wt + 3 * 16384, xlf, xr, N);
    gat_fused_kernel<1, false><<<node_grid, 256, 0, stream>>>(
        xlf, xr, att2, b2, start, sorted_src, out, nullptr, nullptr, N);
}

// Round 7
// 305.723 us; speedup vs baseline: 1.4771x; 1.0358x over previous
//
#include <hip/hip_runtime.h>

#define NEG_SLOPE 0.2f
#define NPB 256          // nodes per dst-bucket (bucket = dst >> 8)
#define CHUNK 4096       // edges per partition block

typedef _Float16 f16x8 __attribute__((ext_vector_type(8)));
typedef _Float16 f16x4 __attribute__((ext_vector_type(4)));
typedef _Float16 f16x2 __attribute__((ext_vector_type(2)));
typedef float    f32x4 __attribute__((ext_vector_type(4)));

#if defined(__has_builtin)
#if __has_builtin(__builtin_amdgcn_fdot2)
#define HAVE_FDOT2 1
#endif
#endif

__device__ __forceinline__ f32x4 cvt4(f16x4 v) {
    return __builtin_convertvector(v, f32x4);
}

// ---------------------------------------------------------------------------
// prep: W transpose->fp16 (blocks 0..255), x fp32->fp16 hi/lo split
// (blocks 256..), bcnt zero (block 0).
// ---------------------------------------------------------------------------
__global__ __launch_bounds__(256) void prep_kernel(
    const float* __restrict__ W0, const float* __restrict__ W1,
    const float* __restrict__ W2, const float* __restrict__ W3,
    _Float16* __restrict__ wt,
    const float* __restrict__ x, _Float16* __restrict__ xh,
    _Float16* __restrict__ xlo, int total, int* __restrict__ bcnt)
{
    int t = threadIdx.x;
    if (blockIdx.x < 256) {
        if (blockIdx.x == 0) bcnt[t] = 0;
        int idx = blockIdx.x * 256 + t;     // 4*128*128
        int m = idx >> 14;
        int k = (idx >> 7) & 127;
        int n = idx & 127;
        const float* W = (m == 0) ? W0 : (m == 1) ? W1 : (m == 2) ? W2 : W3;
        wt[m * 16384 + n * 128 + k] = (_Float16)W[k * 128 + n];
    } else {
        int i = (blockIdx.x - 256) * 256 + t;
        if (i * 2 < total) {
            float2 f = *(const float2*)(x + (size_t)i * 2);
            _Float16 h0 = (_Float16)f.x, h1 = (_Float16)f.y;
            _Float16 l0 = (_Float16)(f.x - (float)h0), l1 = (_Float16)(f.y - (float)h1);
            *(f16x2*)(xh  + (size_t)i * 2) = (f16x2){h0, h1};
            *(f16x2*)(xlo + (size_t)i * 2) = (f16x2){l0, l1};
        }
    }
}

// ---------------------------------------------------------------------------
// fp16 MFMA GEMM, LDS-staged W (34 KB). C = Ah@W + Al@W, fp32 acc.
// Both outputs stored fp16 (y==0 -> Cl, y==1 -> Cr).
// ---------------------------------------------------------------------------
__global__ __launch_bounds__(256) void gemm_f16_kernel(
    const _Float16* __restrict__ Ahi, const _Float16* __restrict__ Alo,
    const _Float16* __restrict__ Wt0, const _Float16* __restrict__ Wt1,
    _Float16* __restrict__ Cl, _Float16* __restrict__ Cr, int N)
{
    const _Float16* Wt = blockIdx.y ? Wt1 : Wt0;
    _Float16* C = blockIdx.y ? Cr : Cl;

    __shared__ _Float16 ldsW[128 * 136];   // row stride 272 B

    const int tid = threadIdx.x;
    const int wave = tid >> 6;
    const int lane = tid & 63;
    const int mrow = lane & 15;
    const int quad = lane >> 4;
    const int rbase = blockIdx.x * 128 + wave * 32;

    // staging loads first (latency overlaps A loads)
    const int sn = tid >> 1, shf = tid & 1;
    float4 stg[8];
    {
        const float4* g = (const float4*)(Wt + sn * 128 + shf * 64);
#pragma unroll
        for (int j = 0; j < 8; j++) stg[j] = g[j];
    }

    f16x8 ah[2][4], al[2][4];
#pragma unroll
    for (int rt = 0; rt < 2; rt++) {
        int r = rbase + rt * 16 + mrow;
        if (r > N - 1) r = N - 1;
        const _Float16* pa = Ahi + (size_t)r * 128 + quad * 8;
        const _Float16* pl = Alo + (size_t)r * 128 + quad * 8;
#pragma unroll
        for (int s = 0; s < 4; s++) {
            ah[rt][s] = *(const f16x8*)(pa + s * 32);
            al[rt][s] = *(const f16x8*)(pl + s * 32);
        }
    }

    {
        float4* d = (float4*)&ldsW[sn * 136 + shf * 64];
#pragma unroll
        for (int j = 0; j < 8; j++) d[j] = stg[j];
    }

    f32x4 acc[2][8];
#pragma unroll
    for (int rt = 0; rt < 2; rt++)
#pragma unroll
        for (int c = 0; c < 8; c++) acc[rt][c] = (f32x4){0.f, 0.f, 0.f, 0.f};

    __syncthreads();

#pragma unroll
    for (int s = 0; s < 4; s++) {
#pragma unroll
        for (int c = 0; c < 8; c++) {
            f16x8 bw = *(const f16x8*)&ldsW[(c * 16 + mrow) * 136 + s * 32 + quad * 8];
            acc[0][c] = __builtin_amdgcn_mfma_f32_16x16x32_f16(ah[0][s], bw, acc[0][c], 0, 0, 0);
            acc[0][c] = __builtin_amdgcn_mfma_f32_16x16x32_f16(al[0][s], bw, acc[0][c], 0, 0, 0);
            acc[1][c] = __builtin_amdgcn_mfma_f32_16x16x32_f16(ah[1][s], bw, acc[1][c], 0, 0, 0);
            acc[1][c] = __builtin_amdgcn_mfma_f32_16x16x32_f16(al[1][s], bw, acc[1][c], 0, 0, 0);
        }
    }

    // D mapping: col = lane&15, row = quad*4 + reg
#pragma unroll
    for (int rt = 0; rt < 2; rt++)
#pragma unroll
        for (int i = 0; i < 4; i++) {
            int r = rbase + rt * 16 + quad * 4 + i;
            if (r < N) {
                _Float16* cr = C + (size_t)r * 128 + mrow;
#pragma unroll
                for (int c = 0; c < 8; c++) cr[c * 16] = (_Float16)acc[rt][c][i];
            }
        }
}

// ---------------------------------------------------------------------------
// Bucketed CSR build (bucket = dst>>8): writes stay CU/XCD-local.
// ---------------------------------------------------------------------------
__global__ __launch_bounds__(256) void histB_kernel(
    const int* __restrict__ ei, int* __restrict__ bcnt, int E)
{
    __shared__ int bh[256];
    int t = threadIdx.x;
    bh[t] = 0;
    __syncthreads();
    int base = blockIdx.x * CHUNK;
#pragma unroll
    for (int j = 0; j < CHUNK / 256; j++) {
        int e = base + t + j * 256;
        if (e < E) atomicAdd(&bh[ei[E + e] >> 8], 1);
    }
    __syncthreads();
    if (bh[t]) atomicAdd(&bcnt[t], bh[t]);
}

__global__ __launch_bounds__(256) void scanB_kernel(
    const int* __restrict__ bcnt, int* __restrict__ bstart,
    int* __restrict__ gcursor, int NB, int E)
{
    __shared__ int s[256];
    int t = threadIdx.x;
    int v = (t < NB) ? bcnt[t] : 0;
    s[t] = v;
    __syncthreads();
    for (int off = 1; off < 256; off <<= 1) {
        int u = (t >= off) ? s[t - off] : 0;
        __syncthreads();
        s[t] += u;
        __syncthreads();
    }
    if (t < NB) { bstart[t] = s[t] - v; gcursor[t] = s[t] - v; }
    if (t == 0) bstart[NB] = E;
}

__global__ __launch_bounds__(256) void passA_kernel(
    const int* __restrict__ ei, int* __restrict__ gcursor,
    int2* __restrict__ staging, int E)
{
    __shared__ int bh[256];
    __shared__ int bbase[256];
    int t = threadIdx.x;
    bh[t] = 0;
    __syncthreads();
    int base = blockIdx.x * CHUNK;
    int srcv[16], dstv[16], rb[16];
#pragma unroll
    for (int j = 0; j < 16; j++) {
        int e = base + t + j * 256;
        if (e < E) {
            int d = ei[E + e];
            srcv[j] = ei[e];
            dstv[j] = d;
            int bk = d >> 8;
            int r = atomicAdd(&bh[bk], 1);
            rb[j] = (r << 8) | bk;
        } else rb[j] = -1;
    }
    __syncthreads();
    if (bh[t]) bbase[t] = atomicAdd(&gcursor[t], bh[t]);
    __syncthreads();
#pragma unroll
    for (int j = 0; j < 16; j++) {
        if (rb[j] >= 0) {
            int bk = rb[j] & 255, r = rb[j] >> 8;
            staging[bbase[bk] + r] = make_int2(srcv[j], dstv[j]);
        }
    }
}

__global__ __launch_bounds__(256) void passB_kernel(
    const int2* __restrict__ staging, const int* __restrict__ bstart,
    int* __restrict__ start, int* __restrict__ sorted_src, int N, int E)
{
    __shared__ int lhist[256], lscan[256], lcur[256];
    int b = blockIdx.x, t = threadIdx.x;
    int r0 = bstart[b], r1 = bstart[b + 1];
    lhist[t] = 0;
    __syncthreads();
    for (int i = r0 + t; i < r1; i += 256) atomicAdd(&lhist[staging[i].y & 255], 1);
    __syncthreads();
    int v = lhist[t];
    lscan[t] = v;
    __syncthreads();
    for (int off = 1; off < 256; off <<= 1) {
        int u = (t >= off) ? lscan[t - off] : 0;
        __syncthreads();
        lscan[t] += u;
        __syncthreads();
    }
    int excl = lscan[t] - v;
    int node = b * NPB + t;
    if (node < N) start[node] = r0 + excl;
    lcur[t] = excl;
    if (b == 0 && t == 0) start[N] = E;
    __syncthreads();
    for (int i = r0 + t; i < r1; i += 256) {
        int2 p = staging[i];
        int rank = atomicAdd(&lcur[p.y & 255], 1);
        sorted_src[r0 + rank] = p.x;
    }
}

// ---------------------------------------------------------------------------
// Fused score+softmax+aggregate, packed-fp16 score path.
// One wave per dst node; each half-wave owns an edge (f16x4/lane).
// att pre-scaled by log2(e) -> exp2f. Self-loop = virtual edge 0.
// ---------------------------------------------------------------------------
template <int H, bool BFOUT>
__global__ __launch_bounds__(256) void gat_fused_kernel(
    const _Float16* __restrict__ xl, const _Float16* __restrict__ xr,
    const float* __restrict__ att, const float* __restrict__ bias,
    const int* __restrict__ start, const int* __restrict__ sorted_src,
    float* __restrict__ outf, _Float16* __restrict__ oh,
    _Float16* __restrict__ ol, int N)
{
    int node = blockIdx.x * 4 + (threadIdx.x >> 6);
    if (node >= N) return;
    const int lane = threadIdx.x & 63;
    const int half = lane >> 5;
    const int hl   = lane & 31;
    const int RED  = (H == 2) ? 8 : 16;
    const _Float16 NS = (_Float16)NEG_SLOPE;

    const f16x4 b4 = *(const f16x4*)(xr + (size_t)node * 128 + hl * 4);
    float4 attf = *(const float4*)(att + hl * 4);
    const float L2E = 1.44269504f;
    f16x4 av = {(_Float16)(attf.x * L2E), (_Float16)(attf.y * L2E),
                (_Float16)(attf.z * L2E), (_Float16)(attf.w * L2E)};
#if defined(HAVE_FDOT2)
    f16x2 avlo = __builtin_shufflevector(av, av, 0, 1);
    f16x2 avhi = __builtin_shufflevector(av, av, 2, 3);
#else
    f32x4 avf = cvt4(av);
#endif

#define SCORE(a_, p_) {                                                     \
        f16x4 t_ = (a_) + b4;                                               \
        f16x4 u_ = __builtin_elementwise_max(t_, t_ * NS);                  \
        _Float16 dummy_;                                                    \
        (void)dummy_;                                                       \
        /* dot in fp32 accumulate */                                        \
        p_ = 0.f;                                                           \
        score_dot(u_, p_);                                                  \
    }

    auto score_dot = [&](f16x4 u_, float& p_) {
#if defined(HAVE_FDOT2)
        f16x2 ulo = __builtin_shufflevector(u_, u_, 0, 1);
        f16x2 uhi = __builtin_shufflevector(u_, u_, 2, 3);
        p_ = __builtin_amdgcn_fdot2(ulo, avlo,
             __builtin_amdgcn_fdot2(uhi, avhi, 0.0f, false), false);
#else
        f32x4 uf = cvt4(u_);
        p_ = uf[0] * avf[0] + uf[1] * avf[1] + uf[2] * avf[2] + uf[3] * avf[3];
#endif
    };

    f32x4 acc = (f32x4){0.f, 0.f, 0.f, 0.f};
    float den = 0.f;

    const int s0 = start[node];
    const int s1 = start[node + 1];
    const int M  = s1 - s0 + 1;        // incl. self-loop at iv==0
    const int Ksafe = (M - 1) >> 1;
    const int K     = (M + 1) >> 1;

    int k = 0;
    for (; k + 8 <= Ksafe; k += 8) {
        int src[8]; f16x4 a[8]; float p[8];
#pragma unroll
        for (int j = 0; j < 8; j++) {
            int iv = 2 * (k + j) + half;
            src[j] = (iv == 0) ? node : sorted_src[s0 + iv - 1];
        }
#pragma unroll
        for (int j = 0; j < 8; j++)
            a[j] = *(const f16x4*)(xl + (size_t)src[j] * 128 + hl * 4);
#pragma unroll
        for (int j = 0; j < 8; j++) SCORE(a[j], p[j]);
#pragma unroll
        for (int m = 1; m <= RED; m <<= 1) {
#pragma unroll
            for (int j = 0; j < 8; j++) p[j] += __shfl_xor(p[j], m, 64);
        }
#pragma unroll
        for (int j = 0; j < 8; j++) {
            float e = exp2f(p[j]);
            den += e;
            acc = acc + cvt4(a[j]) * e;
        }
    }
    for (; k + 4 <= Ksafe; k += 4) {
        int src[4]; f16x4 a[4]; float p[4];
#pragma unroll
        for (int j = 0; j < 4; j++) {
            int iv = 2 * (k + j) + half;
            src[j] = (iv == 0) ? node : sorted_src[s0 + iv - 1];
        }
#pragma unroll
        for (int j = 0; j < 4; j++)
            a[j] = *(const f16x4*)(xl + (size_t)src[j] * 128 + hl * 4);
#pragma unroll
        for (int j = 0; j < 4; j++) SCORE(a[j], p[j]);
#pragma unroll
        for (int m = 1; m <= RED; m <<= 1) {
#pragma unroll
            for (int j = 0; j < 4; j++) p[j] += __shfl_xor(p[j], m, 64);
        }
#pragma unroll
        for (int j = 0; j < 4; j++) {
            float e = exp2f(p[j]);
            den += e;
            acc = acc + cvt4(a[j]) * e;
        }
    }
    for (; k < Ksafe; k++) {
        int iv = 2 * k + half;
        int src = (iv == 0) ? node : sorted_src[s0 + iv - 1];
        f16x4 a = *(const f16x4*)(xl + (size_t)src * 128 + hl * 4);
        float p; SCORE(a, p);
#pragma unroll
        for (int m = 1; m <= RED; m <<= 1) p += __shfl_xor(p, m, 64);
        float e = exp2f(p);
        den += e;
        acc = acc + cvt4(a) * e;
    }
    for (; k < K; k++) {               // masked tail (one iteration)
        int iv = 2 * k + half;
        bool valid = iv < M;
        int pos = s0 + (iv > 0 ? iv - 1 : 0);   // sorted_src padded
        int ld = sorted_src[pos];
        int src = (iv == 0) ? node : (valid ? ld : node);
        f16x4 a = *(const f16x4*)(xl + (size_t)src * 128 + hl * 4);
        float p; SCORE(a, p);
#pragma unroll
        for (int m = 1; m <= RED; m <<= 1) p += __shfl_xor(p, m, 64);
        float e = valid ? exp2f(p) : 0.f;
        den += e;
        acc = acc + cvt4(a) * e;
    }
#undef SCORE

    den    += __shfl_xor(den,    32, 64);
    acc[0] += __shfl_xor(acc[0], 32, 64);
    acc[1] += __shfl_xor(acc[1], 32, 64);
    acc[2] += __shfl_xor(acc[2], 32, 64);
    acc[3] += __shfl_xor(acc[3], 32, 64);

    float inv = 1.0f / den;
    float4 bi = *(const float4*)(bias + hl * 4);
    float o0 = acc[0] * inv + bi.x;
    float o1 = acc[1] * inv + bi.y;
    float o2 = acc[2] * inv + bi.z;
    float o3 = acc[3] * inv + bi.w;

    if (lane < 32) {
        if (BFOUT) {   // next layer's A: fp16 hi+lo split
            _Float16 h0 = (_Float16)o0, h1 = (_Float16)o1, h2 = (_Float16)o2, h3 = (_Float16)o3;
            f16x4 hv = {h0, h1, h2, h3};
            f16x4 lv = {(_Float16)(o0 - (float)h0), (_Float16)(o1 - (float)h1),
                        (_Float16)(o2 - (float)h2), (_Float16)(o3 - (float)h3)};
            *(f16x4*)(oh + (size_t)node * 128 + hl * 4) = hv;
            *(f16x4*)(ol + (size_t)node * 128 + hl * 4) = lv;
        } else {
            *(float4*)(outf + (size_t)node * 128 + hl * 4) = make_float4(o0, o1, o2, o3);
        }
    }
}

// ---------------------------------------------------------------------------
extern "C" void kernel_launch(void* const* d_in, const int* in_sizes, int n_in,
                              void* d_out, int out_size, void* d_ws, size_t ws_size,
                              hipStream_t stream)
{
    const float* x    = (const float*)d_in[0];
    const int*   ei   = (const int*)d_in[1];
    const float* Wl1  = (const float*)d_in[3];
    const float* Wr1  = (const float*)d_in[4];
    const float* att1 = (const float*)d_in[5];
    const float* b1   = (const float*)d_in[6];
    const float* Wl2  = (const float*)d_in[7];
    const float* Wr2  = (const float*)d_in[8];
    const float* att2 = (const float*)d_in[9];
    const float* b2   = (const float*)d_in[10];
    float* out = (float*)d_out;

    const int N  = in_sizes[0] / 128;
    const int E  = in_sizes[1] / 2;
    const int NB = (N + NPB - 1) / NPB;

    const size_t nf = (size_t)N * 128;
    _Float16* xlf  = (_Float16*)d_ws;                 // nf fp16 (gather array)
    _Float16* xrf  = xlf + nf;                        // nf fp16
    _Float16* ah   = xrf + nf;                        // nf fp16 (A hi: x, then h)
    _Float16* al   = ah + nf;                         // nf fp16 (A lo)
    _Float16* wt   = al + nf;                         // 4*16384 fp16
    int* bcnt      = (int*)(wt + 4 * 16384);          // 256
    int* bstart    = bcnt + 256;                      // NB+1 (<=257)
    int* gcursor   = bstart + 257;                    // 256
    int* start     = gcursor + 256;                   // N+1
    size_t stgoff  = ((size_t)(start + N + 1) + 7) & ~(size_t)7;
    int2* staging  = (int2*)stgoff;                   // E int2
    int* sorted_src = (int*)(staging + E);            // E + 64 (padded)

    const int grid_chunk = (E + CHUNK - 1) / CHUNK;
    const int node_grid  = (N + 3) / 4;
    const int gemm_gx    = (N + 127) / 128;
    const int split_grid = (int)((nf / 2 + 255) / 256);

    // ---- prep: W->fp16 transposed, x split, bcnt zero ----
    prep_kernel<<<256 + split_grid, 256, 0, stream>>>(
        Wl1, Wr1, Wl2, Wr2, wt, x, ah, al, (int)nf, bcnt);

    // ---- bucketed CSR build (shared by both layers) ----
    histB_kernel<<<grid_chunk, 256, 0, stream>>>(ei, bcnt, E);
    scanB_kernel<<<1, 256, 0, stream>>>(bcnt, bstart, gcursor, NB, E);
    passA_kernel<<<grid_chunk, 256, 0, stream>>>(ei, gcursor, staging, E);
    passB_kernel<<<NB, 256, 0, stream>>>(staging, bstart, start, sorted_src, N, E);

    // ---- Layer 1: heads=2, ch=64 ----
    gemm_f16_kernel<<<dim3(gemm_gx, 2), 256, 0, stream>>>(
        ah, al, wt + 0 * 16384, wt + 1 * 16384, xlf, xrf, N);
    gat_fused_kernel<2, true><<<node_grid, 256, 0, stream>>>(
        xlf, xrf, att1, b1, start, sorted_src, nullptr, ah, al, N);

    // ---- Layer 2: heads=1, ch=128 ----
    gemm_f16_kernel<<<dim3(gemm_gx, 2), 256, 0, stream>>>(
        ah, al, wt + 2 * 16384, wt + 3 * 16384, xlf, xrf, N);
    gat_fused_kernel<1, false><<<node_grid, 256, 0, stream>>>(
        xlf, xrf, att2, b2, start, sorted_src, out, nullptr, nullptr, N);
}